// Round 1
// baseline (215.352 us; speedup 1.0000x reference)
//
#include <hip/hip_runtime.h>
#include <hip/hip_bf16.h>

#define BB 64
#define TT 4096
#define DD 128
#define KK 512

// key(-inf): bits(-inf)=0xFF800000, sign set -> ~u = 0x007FFFFF.
// All finite score keys are >= 0x00800000, so masked tokens sort strictly last.
#define KEY_NEG_INF 0x007FFFFFu

// ---------------------------------------------------------------------------
// Kernel 1: keys[b*T+t] = monotone_uint( dot(emb[b,t,:], W) + b0 ), masked -> key(-inf)
// Each 64-lane wave: 2 tokens/iter (half-wave each), float4 loads (16B/lane,
// wave covers 2 contiguous 512B rows -> perfect coalescing). 5 intra-32
// shfl_xor levels. Double accumulation keeps the top-k set exact vs the fp32
// numpy reference (absmax 0.0 in prior rounds). BW-bound (~21-25 us theory).
// ---------------------------------------------------------------------------
__global__ __launch_bounds__(256) void k_scores(
    const float* __restrict__ emb, const int* __restrict__ mask,
    const float* __restrict__ W, const float* __restrict__ bias,
    unsigned int* __restrict__ keys_out)
{
    const int wave = threadIdx.x >> 6;
    const int lane = threadIdx.x & 63;
    const int half = lane >> 5;        // which token of the pair
    const int sub  = lane & 31;        // dim quarter within token
    const int pair0 = (blockIdx.x * 4 + wave) * 8;   // 16 tokens per wave

    const float4 w = ((const float4*)W)[sub];
    const double w0 = (double)w.x, w1 = (double)w.y, w2 = (double)w.z, w3 = (double)w.w;
    const double b0 = (double)bias[0];

#pragma unroll
    for (int i = 0; i < 8; ++i) {
        const int t = (pair0 + i) * 2 + half;          // global token in [0, B*T)
        const float4 e = ((const float4*)emb)[(size_t)t * 32 + sub];
        double s = (double)e.x * w0 + (double)e.y * w1
                 + (double)e.z * w2 + (double)e.w * w3;
        s += __shfl_xor(s, 16, 64);
        s += __shfl_xor(s,  8, 64);
        s += __shfl_xor(s,  4, 64);
        s += __shfl_xor(s,  2, 64);
        s += __shfl_xor(s,  1, 64);
        if (sub == 0) {
            const float val = (float)(s + b0);
            const unsigned int u = __float_as_uint(val);
            unsigned int key = (u & 0x80000000u) ? ~u : (u | 0x80000000u);
            if (!mask[t]) key = KEY_NEG_INF;
            keys_out[t] = key;
        }
    }
}

// ---------------------------------------------------------------------------
// Kernel 2: per-row exact top-K (ties -> lower index), emitting selected
// token indices in ASCENDING token order + gathered mask as 0/1 floats.
// One 1024-thread block (16 waves) per row.
//
// R0 rework:
//  * keys held in REGISTERS (uint4/thread) — each thread only ever inspects
//    its own 4 keys, so the 16 KB LDS keys buffer + ~24 LDS reads/thread
//    across 4 passes + emission are deleted.
//  * single 256-bin shared histogram (was 16 ways x 257 + per-pass zero +
//    16-way reduce). Passes 1-3 use direct LDS atomics (mantissa bits are
//    near-uniform -> few same-address conflicts).
//  * pass 0 uses wave-leader ballot aggregation: the monotone-float top byte
//    is exponent-dominated (~57% of keys in bin 0xBF), which previously
//    caused ~36-way same-address LDS-atomic serialization. Leaders add
//    popcount(match) once per distinct bin (~12 atomics/wave/round).
// Selection result is bit-identical to the previous version.
// ---------------------------------------------------------------------------
__global__ __launch_bounds__(1024) void k_select(
    const unsigned int* __restrict__ keys_in, const int* __restrict__ mask,
    int* __restrict__ idx_out, float* __restrict__ mask_out)
{
    __shared__ unsigned int hist[256];
    __shared__ unsigned int wsum[16];
    __shared__ unsigned int bcast[2];           // [0]=chosen bin, [1]=new count_above

    const int row  = blockIdx.x;
    const int tid  = threadIdx.x;
    const int wv   = tid >> 6;
    const int lane = tid & 63;
    const unsigned int* krow = keys_in + (size_t)row * TT;
    const int*          mrow = mask    + (size_t)row * TT;

    // Coalesced uint4 load of this thread's 4 keys -> registers (tokens 4t..4t+3).
    const uint4 kv = ((const uint4*)krow)[tid];
    const unsigned int kk[4] = { kv.x, kv.y, kv.z, kv.w };

    unsigned int prefix = 0;        // high bytes decided so far
    unsigned int count_above = 0;   // #keys strictly greater than current range
    for (int pass = 0; pass < 4; ++pass) {
        const int shift = 24 - 8 * pass;
        if (tid < 256) hist[tid] = 0;
        __syncthreads();
        if (pass == 0) {
            // Wave-leader aggregated counting (handles exponent-bin concentration).
#pragma unroll
            for (int i = 0; i < 4; ++i) {
                unsigned int b = kk[i] >> 24;          // always in-group in pass 0
                while (true) {
                    const unsigned long long act = __ballot(b != 0xFFFFFFFFu);
                    if (!act) break;
                    const int leader = __ffsll((unsigned long long)act) - 1;
                    const unsigned int lb = __shfl(b, leader, 64);
                    const unsigned long long match = __ballot(b == lb);
                    if (lane == leader)
                        atomicAdd(&hist[lb], (unsigned int)__popcll(match));
                    if (b == lb) b = 0xFFFFFFFFu;      // consumed
                }
            }
        } else {
#pragma unroll
            for (int i = 0; i < 4; ++i) {
                const unsigned int k = kk[i];
                if ((k >> (shift + 8)) == prefix)
                    atomicAdd(&hist[(k >> shift) & 0xFFu], 1u);
            }
        }
        __syncthreads();
        if (wv == 0) {
            // Descending-bin order: position p = 4*lane+j handles bin 255-p.
            unsigned int v[4], c[4];
            unsigned int run = 0;
#pragma unroll
            for (int j = 0; j < 4; ++j) {
                v[j] = hist[255 - (4 * lane + j)];
                run += v[j];
                c[j] = run;                     // lane-local inclusive
            }
            unsigned int scan = run;
#pragma unroll
            for (int off = 1; off < 64; off <<= 1) {
                const unsigned int u = __shfl_up(scan, off, 64);
                if (lane >= off) scan += u;
            }
            const unsigned int excl_w = scan - run;  // keys in higher bins than this lane's range
#pragma unroll
            for (int j = 0; j < 4; ++j) {
                const unsigned int incl = excl_w + c[j];   // #keys with byte >= bin
                const unsigned int excl = incl - v[j];     // #keys with byte >  bin
                if (count_above + incl >= KK && count_above + excl < KK) {
                    bcast[0] = 255u - (unsigned int)(4 * lane + j);
                    bcast[1] = count_above + excl;
                }
            }
        }
        __syncthreads();
        prefix = (prefix << 8) | bcast[0];
        count_above = bcast[1];
        // No extra barrier: next pass's hist-zero barrier protects bcast reuse.
    }
    const unsigned int vstar = prefix;            // exact key of Kth largest
    const unsigned int need  = KK - count_above;  // #ties to take, lowest index first

    // ---- emit selected indices in ascending token order ----
    unsigned int gt = 0, eq = 0;
#pragma unroll
    for (int i = 0; i < 4; ++i) {
        gt += (kk[i] > vstar);
        eq += (kk[i] == vstar);
    }
    unsigned int packed = (gt << 16) | eq;        // counts <= 4096, no overflow
    unsigned int scan = packed;
#pragma unroll
    for (int off = 1; off < 64; off <<= 1) {
        const unsigned int u = __shfl_up(scan, off, 64);
        if (lane >= off) scan += u;
    }
    if (lane == 63) wsum[wv] = scan;
    __syncthreads();
    unsigned int add = 0;
    for (int w = 0; w < wv; ++w) add += wsum[w];  // LDS broadcast reads
    const unsigned int before = scan - packed + add;  // block-exclusive prefix
    unsigned int gt_b = before >> 16;
    unsigned int eq_b = before & 0xFFFFu;
#pragma unroll
    for (int i = 0; i < 4; ++i) {
        const int t = tid * 4 + i;
        const unsigned int k = kk[i];
        if (k > vstar) {
            const unsigned int pos = gt_b + (eq_b < need ? eq_b : need);
            idx_out[row * KK + pos]  = t;
            mask_out[row * KK + pos] = mrow[t] ? 1.0f : 0.0f;
            gt_b++;
        } else if (k == vstar) {
            if (eq_b < need) {
                const unsigned int pos = gt_b + eq_b;
                idx_out[row * KK + pos]  = t;
                mask_out[row * KK + pos] = mrow[t] ? 1.0f : 0.0f;
            }
            eq_b++;
        }
    }
}

// ---------------------------------------------------------------------------
// Kernel 3: out[b,j,:] = emb[b, idx[b*K+j], :]
// 32 lanes x float4 = 128 floats per selected row; 8 rows per 256-thread block.
// Reads are L3-resident (emb just streamed by k_scores); writes HBM. Kept as a
// separate full-grid kernel: fusing into the 64-block k_select would throttle
// the 32 MiB move to ~64 CUs' worth of BW.
// ---------------------------------------------------------------------------
__global__ __launch_bounds__(256) void k_gather(
    const float* __restrict__ emb, const int* __restrict__ idx,
    float* __restrict__ out)
{
    const int gp   = blockIdx.x * 8 + (threadIdx.x >> 5);  // selected-row index in [0, B*K)
    const int lane = threadIdx.x & 31;
    const int b = gp >> 9;                                  // / KK
    const int t = idx[gp];
    const float4* src = (const float4*)(emb + ((size_t)b * TT + t) * DD);
    float4*       dst = (float4*)(out + (size_t)gp * DD);
    dst[lane] = src[lane];
}

extern "C" void kernel_launch(void* const* d_in, const int* in_sizes, int n_in,
                              void* d_out, int out_size, void* d_ws, size_t ws_size,
                              hipStream_t stream)
{
    const float* emb  = (const float*)d_in[0];   // (B,T,D) fp32
    const int*   mask = (const int*)d_in[1];     // (B,T) bool -> int32 0/1
    // d_in[2] = k (int scalar) -- fixed at 512 for this problem instance
    const float* W    = (const float*)d_in[3];   // (D,)
    const float* bias = (const float*)d_in[4];   // (1,)

    float* out_sel  = (float*)d_out;                        // B*K*D floats
    float* out_mask = (float*)d_out + (size_t)BB * KK * DD; // B*K floats

    unsigned int* keys = (unsigned int*)d_ws;                                  // B*T uints (1 MB)
    int*          idx  = (int*)((char*)d_ws + (size_t)BB * TT * sizeof(unsigned int)); // B*K ints

    k_scores<<<BB * TT / 64, 256, 0, stream>>>(emb, mask, W, bias, keys);
    k_select<<<BB, 1024, 0, stream>>>(keys, mask, idx, out_mask);
    k_gather<<<BB * KK / 8, 256, 0, stream>>>(emb, idx, out_sel);
}